// Round 5
// baseline (335.287 us; speedup 1.0000x reference)
//
#include <hip/hip_runtime.h>
#include <stdint.h>
#include <math.h>

// Problem geometry (B=32, C=384, H=W=56), float32 in/out.
#define TOTAL_N 38535168   // 32*384*56*56
#define HW_SZ   3136       // 56*56  (multiple of 16 -> 16 consecutive elems share a channel)
#define NCH     384
#define EPT     16         // elements per thread

typedef float f32x4 __attribute__((ext_vector_type(4)));

__device__ __forceinline__ uint32_t rotl32(uint32_t x, int r) {
  return (x << r) | (x >> (32 - r));  // LLVM -> v_alignbit_b32
}

// ---------------------------------------------------------------------------
// JAX partitionable threefry (verified bit-exact in R3/R4):
//   bits[i] = o0 ^ o1, (o0,o1) = threefry2x32(key=(0,42), counter=(0, i))
// ---------------------------------------------------------------------------
__device__ __forceinline__ uint32_t tf_bits(uint32_t i) {
  const uint32_t ks0 = 0u;
  const uint32_t ks1 = 42u;
  const uint32_t ks2 = 0x1BD11BDAu ^ 0u ^ 42u;  // 0x1BD11BF0

  uint32_t x0 = 0u + ks0;   // counter_hi + ks[0]
  uint32_t x1 = i + ks1;    // counter_lo + ks[1]

#define TF_R(r) { x0 += x1; x1 = rotl32(x1, (r)) ^ x0; }
  TF_R(13) TF_R(15) TF_R(26) TF_R(6)
  x0 += ks1; x1 += ks2 + 1u;
  TF_R(17) TF_R(29) TF_R(16) TF_R(24)
  x0 += ks2; x1 += ks0 + 2u;
  TF_R(13) TF_R(15) TF_R(26) TF_R(6)
  x0 += ks0; x1 += ks1 + 3u;
  TF_R(17) TF_R(29) TF_R(16) TF_R(24)
  x0 += ks1; x1 += ks2 + 4u;
  TF_R(13) TF_R(15) TF_R(26) TF_R(6)
  x0 += ks2; x1 += ks0 + 5u;
#undef TF_R

  return x0 ^ x1;
}

// ---------------------------------------------------------------------------
// Prep: keep_prob[c] in exact reference rounding order, folded into an
// integer threshold: u < kp  <=>  bits < (ceil(kp*2^23) << 9)   (exact)
// ---------------------------------------------------------------------------
__global__ __launch_bounds__(64) void prep_thresholds(
    const float* __restrict__ fi, uint32_t* __restrict__ thr9) {
  int t = threadIdx.x;  // 0..63
  float mn = fi[t];
  float mx = mn;
  for (int c = t + 64; c < NCH; c += 64) {
    float v = fi[c];
    mn = fminf(mn, v);
    mx = fmaxf(mx, v);
  }
  for (int off = 1; off < 64; off <<= 1) {
    mn = fminf(mn, __shfl_xor(mn, off));
    mx = fmaxf(mx, __shfl_xor(mx, off));
  }
  float denom = __fsub_rn(mx, mn);
  for (int c = t; c < NCH; c += 64) {
    float scaled = __fdiv_rn(__fsub_rn(fi[c], mn), denom);
    float one_minus = __fsub_rn(1.0f, scaled);
    float rates = __fadd_rn(0.1f, __fmul_rn(0.4f, one_minus));
    float kp = __fsub_rn(1.0f, rates);  // reference rounding order
    uint32_t thr = (uint32_t)ceil((double)kp * 8388608.0);  // exact in double
    thr9[c] = thr << 9;
  }
}

// ---------------------------------------------------------------------------
// Main: 16 consecutive elements per thread. Loads issued up-front; 16
// independent hash chains fill the latency shadow. Non-temporal stores keep
// the L3-resident input from being evicted by the output stream.
// Grid is exact: TOTAL_N / (256*16) = 9408 blocks, no tail branch.
// ---------------------------------------------------------------------------
__global__ __launch_bounds__(256) void dropout_kernel(
    const float* __restrict__ x, const uint32_t* __restrict__ thr9,
    float* __restrict__ out) {
  int tid = blockIdx.x * 256 + threadIdx.x;
  int i0 = tid << 4;

  uint32_t thr = thr9[(i0 / HW_SZ) % NCH];  // 16 | 3136 -> one channel/thread

  // Issue all input loads first (independent of the hash work).
  f32x4 xv[4];
#pragma unroll
  for (int k = 0; k < 4; ++k)
    xv[k] = *reinterpret_cast<const f32x4*>(x + i0 + 4 * k);

  f32x4 ov[4];
#pragma unroll
  for (int k = 0; k < 4; ++k) {
#pragma unroll
    for (int j = 0; j < 4; ++j) {
      uint32_t b = tf_bits((uint32_t)(i0 + 4 * k + j));
      ov[k][j] = (b < thr) ? xv[k][j] : 0.0f;
    }
  }

#pragma unroll
  for (int k = 0; k < 4; ++k)
    __builtin_nontemporal_store(ov[k], reinterpret_cast<f32x4*>(out + i0 + 4 * k));
}

extern "C" void kernel_launch(void* const* d_in, const int* in_sizes, int n_in,
                              void* d_out, int out_size, void* d_ws, size_t ws_size,
                              hipStream_t stream) {
  const float* x = (const float*)d_in[0];
  const float* fi = (const float*)d_in[1];
  float* out = (float*)d_out;
  uint32_t* thr9 = (uint32_t*)d_ws;  // 384 u32 of scratch

  prep_thresholds<<<1, 64, 0, stream>>>(fi, thr9);

  const int blocks = TOTAL_N / (256 * EPT);  // 9408 exact
  dropout_kernel<<<blocks, 256, 0, stream>>>(x, thr9, out);
}

// Round 7
// 272.710 us; speedup vs baseline: 1.2295x; 1.2295x over previous
//
#include <hip/hip_runtime.h>
#include <stdint.h>
#include <math.h>

// Problem geometry (B=32, C=384, H=W=56), float32 in/out.
#define TOTAL_N 38535168   // 32*384*56*56
#define HW_SZ   3136       // 56*56
#define NCH     384

typedef float f32x4 __attribute__((ext_vector_type(4)));

__device__ __forceinline__ uint32_t rotl32(uint32_t x, int r) {
  return (x << r) | (x >> (32 - r));  // LLVM -> v_alignbit_b32
}

// ---------------------------------------------------------------------------
// JAX partitionable threefry (verified bit-exact R3/R4/R5):
//   bits[i] = o0 ^ o1, (o0,o1) = threefry2x32(key=(0,42), counter=(0, i))
// ---------------------------------------------------------------------------
__device__ __forceinline__ uint32_t tf_bits(uint32_t i) {
  const uint32_t ks0 = 0u;
  const uint32_t ks1 = 42u;
  const uint32_t ks2 = 0x1BD11BDAu ^ 0u ^ 42u;  // 0x1BD11BF0

  uint32_t x0 = 0u + ks0;
  uint32_t x1 = i + ks1;

#define TF_R(r) { x0 += x1; x1 = rotl32(x1, (r)) ^ x0; }
  TF_R(13) TF_R(15) TF_R(26) TF_R(6)
  x0 += ks1; x1 += ks2 + 1u;
  TF_R(17) TF_R(29) TF_R(16) TF_R(24)
  x0 += ks2; x1 += ks0 + 2u;
  TF_R(13) TF_R(15) TF_R(26) TF_R(6)
  x0 += ks0; x1 += ks1 + 3u;
  TF_R(17) TF_R(29) TF_R(16) TF_R(24)
  x0 += ks1; x1 += ks2 + 4u;
  TF_R(13) TF_R(15) TF_R(26) TF_R(6)
  x0 += ks2; x1 += ks0 + 5u;
#undef TF_R

  return x0 ^ x1;
}

// ---------------------------------------------------------------------------
// Prep: keep_prob[c] in exact reference rounding order, folded into an
// integer threshold: u < kp  <=>  bits < (ceil(kp*2^23) << 9)   (exact)
// ---------------------------------------------------------------------------
__global__ __launch_bounds__(64) void prep_thresholds(
    const float* __restrict__ fi, uint32_t* __restrict__ thr9) {
  int t = threadIdx.x;  // 0..63
  float mn = fi[t];
  float mx = mn;
  for (int c = t + 64; c < NCH; c += 64) {
    float v = fi[c];
    mn = fminf(mn, v);
    mx = fmaxf(mx, v);
  }
  for (int off = 1; off < 64; off <<= 1) {
    mn = fminf(mn, __shfl_xor(mn, off));
    mx = fmaxf(mx, __shfl_xor(mx, off));
  }
  float denom = __fsub_rn(mx, mn);
  for (int c = t; c < NCH; c += 64) {
    float scaled = __fdiv_rn(__fsub_rn(fi[c], mn), denom);
    float one_minus = __fsub_rn(1.0f, scaled);
    float rates = __fadd_rn(0.1f, __fmul_rn(0.4f, one_minus));
    float kp = __fsub_rn(1.0f, rates);  // reference rounding order
    uint32_t thr = (uint32_t)ceil((double)kp * 8388608.0);  // exact in double
    thr9[c] = thr << 9;
  }
}

// ---------------------------------------------------------------------------
// Main: block owns 2048 contiguous elements; thread t handles float4 chunks
// at base + t*4 and base + 1024 + t*4  ->  every load/store instruction has
// consecutive lanes on consecutive 16B (perfect coalescing; L2 write-combines
// full lines). 4 | 3136 -> each float4 chunk lies in one channel.
// Grid exact: TOTAL_N / 2048 = 18816 blocks, no tail branch.
// ---------------------------------------------------------------------------
__global__ __launch_bounds__(256) void dropout_kernel(
    const float* __restrict__ x, const uint32_t* __restrict__ thr9,
    float* __restrict__ out) {
  const int base = blockIdx.x * 2048 + threadIdx.x * 4;
  const int iA = base;           // chunk A
  const int iB = base + 1024;    // chunk B

  uint32_t thrA = thr9[(iA / HW_SZ) % NCH];
  uint32_t thrB = thr9[(iB / HW_SZ) % NCH];

  f32x4 xa = *reinterpret_cast<const f32x4*>(x + iA);
  f32x4 xb = *reinterpret_cast<const f32x4*>(x + iB);
  f32x4 oa, ob;

#pragma unroll
  for (int j = 0; j < 4; ++j) {
    uint32_t ba = tf_bits((uint32_t)(iA + j));
    uint32_t bb = tf_bits((uint32_t)(iB + j));
    oa[j] = (ba < thrA) ? xa[j] : 0.0f;
    ob[j] = (bb < thrB) ? xb[j] : 0.0f;
  }

  *reinterpret_cast<f32x4*>(out + iA) = oa;
  *reinterpret_cast<f32x4*>(out + iB) = ob;
}

extern "C" void kernel_launch(void* const* d_in, const int* in_sizes, int n_in,
                              void* d_out, int out_size, void* d_ws, size_t ws_size,
                              hipStream_t stream) {
  const float* x = (const float*)d_in[0];
  const float* fi = (const float*)d_in[1];
  float* out = (float*)d_out;
  uint32_t* thr9 = (uint32_t*)d_ws;  // 384 u32 of scratch

  prep_thresholds<<<1, 64, 0, stream>>>(fi, thr9);

  const int blocks = TOTAL_N / 2048;  // 18816 exact
  dropout_kernel<<<blocks, 256, 0, stream>>>(x, thr9, out);
}